// Round 1
// baseline (66.927 us; speedup 1.0000x reference)
//
#include <hip/hip_runtime.h>

// 2x2 non-overlapping max pool, fp32.
// X: (B=16, C=64, H=256, W=256) -> out: (16, 64, 128, 128)
// Memory-bound: 256 MiB read + 64 MiB write. Strategy: each thread
// processes one float4 from each of two input rows -> one float2 output.

#define W_IN 256
#define H_IN 256
#define W_OUT 128
#define H_OUT 128

__global__ __launch_bounds__(256) void maxpool2x2_kernel(
    const float* __restrict__ X, float* __restrict__ out, int n_pairs) {
    // One "unit" = 2 consecutive output elements in w (one float2 store).
    // Units per output row: W_OUT/2 = 64.
    // out_row index r in [0, B*C*H_OUT): plane p = r >> 7, h_out = r & 127.
    int stride = gridDim.x * blockDim.x;
    for (int t = blockIdx.x * blockDim.x + threadIdx.x; t < n_pairs; t += stride) {
        int r    = t >> 6;        // which output row (b,c,h_out flattened)
        int pair = t & 63;        // which float2 within the row
        int p     = r >> 7;       // plane = b*C + c
        int h_out = r & 127;

        // input base for this 2x4 patch
        long in_off = (long)p * (H_IN * W_IN) + (long)(2 * h_out) * W_IN + pair * 4;
        const float4 r0 = *reinterpret_cast<const float4*>(X + in_off);
        const float4 r1 = *reinterpret_cast<const float4*>(X + in_off + W_IN);

        float2 o;
        o.x = fmaxf(fmaxf(r0.x, r0.y), fmaxf(r1.x, r1.y));
        o.y = fmaxf(fmaxf(r0.z, r0.w), fmaxf(r1.z, r1.w));

        long out_off = (long)r * W_OUT + pair * 2;
        *reinterpret_cast<float2*>(out + out_off) = o;
    }
}

extern "C" void kernel_launch(void* const* d_in, const int* in_sizes, int n_in,
                              void* d_out, int out_size, void* d_ws, size_t ws_size,
                              hipStream_t stream) {
    const float* X = (const float*)d_in[0];
    float* out = (float*)d_out;

    // total output elements = out_size; units of 2 outputs each
    int n_pairs = out_size / 2;  // 8,388,608
    int block = 256;
    int grid = 2048;  // grid-stride; ~16 iterations per thread
    maxpool2x2_kernel<<<grid, block, 0, stream>>>(X, out, n_pairs);
}

// Round 2
// 60.381 us; speedup vs baseline: 1.1084x; 1.1084x over previous
//
#include <hip/hip_runtime.h>

// 2x2 non-overlapping max pool, fp32.
// X: (B=16, C=64, H=256, W=256) -> out: (16, 64, 128, 128)
// Memory-bound streaming: 256 MiB read once + 64 MiB write once, no reuse.
// -> nontemporal loads/stores (bypass L2/L3 pollution), float4-wide I/O.
// Each thread: 2 rows x 2 float4 loads (32 B/row) -> 1 float4 store (4 outputs).

#define W_IN 256
#define H_IN 256
#define W_OUT 128
#define H_OUT 128

typedef float f4 __attribute__((ext_vector_type(4)));

__global__ __launch_bounds__(256) void maxpool2x2_kernel(
    const float* __restrict__ X, float* __restrict__ out, int n_units) {
    // One unit = 4 consecutive output elements in w (one float4 store).
    // Units per output row: W_OUT/4 = 32.
    int stride = gridDim.x * blockDim.x;
    for (int t = blockIdx.x * blockDim.x + threadIdx.x; t < n_units; t += stride) {
        int r    = t >> 5;        // output row (b,c,h_out flattened)
        int unit = t & 31;        // which float4 within the row
        int p     = r >> 7;       // plane = b*C + c
        int h_out = r & 127;

        long in_off = (long)p * (H_IN * W_IN) + (long)(2 * h_out) * W_IN + unit * 8;
        const f4* src0 = reinterpret_cast<const f4*>(X + in_off);
        const f4* src1 = reinterpret_cast<const f4*>(X + in_off + W_IN);
        f4 a0 = __builtin_nontemporal_load(src0);
        f4 a1 = __builtin_nontemporal_load(src0 + 1);
        f4 b0 = __builtin_nontemporal_load(src1);
        f4 b1 = __builtin_nontemporal_load(src1 + 1);

        f4 o;
        o.x = fmaxf(fmaxf(a0.x, a0.y), fmaxf(b0.x, b0.y));
        o.y = fmaxf(fmaxf(a0.z, a0.w), fmaxf(b0.z, b0.w));
        o.z = fmaxf(fmaxf(a1.x, a1.y), fmaxf(b1.x, b1.y));
        o.w = fmaxf(fmaxf(a1.z, a1.w), fmaxf(b1.z, b1.w));

        long out_off = (long)r * W_OUT + unit * 4;
        __builtin_nontemporal_store(o, reinterpret_cast<f4*>(out + out_off));
    }
}

extern "C" void kernel_launch(void* const* d_in, const int* in_sizes, int n_in,
                              void* d_out, int out_size, void* d_ws, size_t ws_size,
                              hipStream_t stream) {
    const float* X = (const float*)d_in[0];
    float* out = (float*)d_out;

    int n_units = out_size / 4;  // 4,194,304
    int block = 256;
    int grid = 2048;  // grid-stride; ~8 iterations per thread
    maxpool2x2_kernel<<<grid, block, 0, stream>>>(X, out, n_units);
}

// Round 3
// 57.539 us; speedup vs baseline: 1.1632x; 1.0494x over previous
//
#include <hip/hip_runtime.h>

// 2x2 non-overlapping max pool, fp32.
// X: (B=16, C=64, H=256, W=256) -> out: (16, 64, 128, 128)
// Memory-bound streaming: 256 MiB read once + 64 MiB write once, no reuse.
// Nontemporal loads/stores; flat one-unit-per-thread launch (no loop):
// every wave issues its 4 independent 16B loads immediately -> max MLP.
// Each thread: 2 rows x 2 float4 loads -> 1 float4 store (4 outputs).

#define W_IN 256
#define H_IN 256
#define W_OUT 128
#define H_OUT 128

typedef float f4 __attribute__((ext_vector_type(4)));

__global__ __launch_bounds__(256) void maxpool2x2_kernel(
    const float* __restrict__ X, float* __restrict__ out) {
    // One unit = 4 consecutive output elements in w (one float4 store).
    // Units per output row: W_OUT/4 = 32. Grid covers all units exactly.
    int t = blockIdx.x * 256 + threadIdx.x;
    int r    = t >> 5;        // output row (b,c,h_out flattened)
    int unit = t & 31;        // which float4 within the row
    int p     = r >> 7;       // plane = b*C + c
    int h_out = r & 127;

    long in_off = (long)p * (H_IN * W_IN) + (long)(2 * h_out) * W_IN + unit * 8;
    const f4* src0 = reinterpret_cast<const f4*>(X + in_off);
    const f4* src1 = reinterpret_cast<const f4*>(X + in_off + W_IN);
    f4 a0 = __builtin_nontemporal_load(src0);
    f4 a1 = __builtin_nontemporal_load(src0 + 1);
    f4 b0 = __builtin_nontemporal_load(src1);
    f4 b1 = __builtin_nontemporal_load(src1 + 1);

    f4 o;
    o.x = fmaxf(fmaxf(a0.x, a0.y), fmaxf(b0.x, b0.y));
    o.y = fmaxf(fmaxf(a0.z, a0.w), fmaxf(b0.z, b0.w));
    o.z = fmaxf(fmaxf(a1.x, a1.y), fmaxf(b1.x, b1.y));
    o.w = fmaxf(fmaxf(a1.z, a1.w), fmaxf(b1.z, b1.w));

    long out_off = (long)r * W_OUT + unit * 4;
    __builtin_nontemporal_store(o, reinterpret_cast<f4*>(out + out_off));
}

extern "C" void kernel_launch(void* const* d_in, const int* in_sizes, int n_in,
                              void* d_out, int out_size, void* d_ws, size_t ws_size,
                              hipStream_t stream) {
    const float* X = (const float*)d_in[0];
    float* out = (float*)d_out;

    int n_units = out_size / 4;        // 4,194,304
    int grid = n_units / 256;          // 16,384 blocks, exact cover
    maxpool2x2_kernel<<<grid, 256, 0, stream>>>(X, out);
}